// Round 11
// baseline (1147.070 us; speedup 1.0000x reference)
//
#include <hip/hip_runtime.h>
#include <hip/hip_bf16.h>
#include <hip/hip_fp16.h>

typedef __hip_bfloat16 bf16;
typedef unsigned short u16;
typedef __attribute__((ext_vector_type(8))) short short8;
typedef __attribute__((ext_vector_type(4))) float floatx4;
typedef _Float16 half8 __attribute__((ext_vector_type(8)));

static constexpr int Nn = 25000;   // nodes
static constexpr int Ne = 400000;  // edges
static constexpr int Bg = 64;      // graphs

__device__ __forceinline__ float ldf(const void* p, size_t i, bool b16) {
  return b16 ? __bfloat162float(((const bf16*)p)[i]) : ((const float*)p)[i];
}

// ---------------- dtype detection ----------------
__global__ void detect_kernel(const u16* a, int n, const u16* b, int m, int* flags) {
  __shared__ int c0, c1;
  if (threadIdx.x == 0) { c0 = 0; c1 = 0; }
  __syncthreads();
  int t = threadIdx.x;
  int l0 = 0, l1 = 0;
  for (int i = t; i < n; i += 256) {
    unsigned e = (a[i] >> 7) & 0xFF;
    if (e >= 140) l0++;
  }
  for (int i = t; i < m; i += 256) {
    unsigned e = (b[i] >> 7) & 0xFF;
    if (e >= 140) l1++;
  }
  atomicAdd(&c0, l0);
  atomicAdd(&c1, l1);
  __syncthreads();
  if (t == 0) {
    flags[0] = (c0 < n / 16) ? 1 : 0;
    flags[1] = (c1 < m / 16) ? 1 : 0;
  }
}

// ------- fused transpose+convert: all big weights -> fp16 plane [N][K] ----------------
struct TC { const void* W; size_t off; __half* H; int K; int N; int start; };
struct TCAll { TC t[10]; int total; };

__global__ void transconv_all_kernel(TCAll a, const int* __restrict__ pflag) {
  const bool pb = (*pflag != 0);
  int idx = blockIdx.x * 256 + threadIdx.x;
  if (idx >= a.total) return;
  int s = 0;
  while (s + 1 < 10 && idx >= a.t[s + 1].start) s++;
  int li = idx - a.t[s].start;
  int K = a.t[s].K, N = a.t[s].N;
  int k = li / N, n = li - k * N;
  float w = ldf(a.t[s].W, a.t[s].off + li, pb);
  a.t[s].H[(size_t)n * K + k] = __float2half(w);
}

// ---------------- fp16 MFMA GEMM (branch dim = blockIdx.z) ----------------
template <int ACT, int OUT>
__global__ __launch_bounds__(256) void mfma_f16_gemm(const __half* __restrict__ A, size_t Abs,
                                                     const __half* __restrict__ Bt, size_t Bbs,
                                                     const void* __restrict__ bias, size_t bstr,
                                                     const int* __restrict__ pflag,
                                                     void* __restrict__ C, size_t Cbs,
                                                     int M, int K, int N) {
  const int br = blockIdx.z;
  A += (size_t)br * Abs;
  Bt += (size_t)br * Bbs;
  const size_t boff = (size_t)br * bstr;
  __shared__ short As[128 * 40];
  __shared__ short Bs[128 * 40];
  const int bm = blockIdx.x * 128;
  const int bn = blockIdx.y * 128;
  const int tid = threadIdx.x;
  const int lane = tid & 63;
  const int wave = tid >> 6;
  const int wm = wave >> 1, wn = wave & 1;
  const int lm = lane & 15, quad = lane >> 4;
  const int srow = tid >> 1;
  const int sseg = tid & 1;
  floatx4 acc[4][4] = {};
  for (int k0 = 0; k0 < K; k0 += 32) {
    bool kv = (k0 + sseg * 16) < K;
    {
      int gr = bm + srow;
      short8 a0 = {}, a1 = {};
      if (gr < M && kv) {
        const short8* gp = (const short8*)(A + (size_t)gr * K + k0 + sseg * 16);
        a0 = gp[0];
        a1 = gp[1];
      }
      *(short8*)&As[srow * 40 + sseg * 16] = a0;
      *(short8*)&As[srow * 40 + sseg * 16 + 8] = a1;
    }
    {
      int gc = bn + srow;
      short8 b0 = {}, b1 = {};
      if (gc < N && kv) {
        const short8* gp = (const short8*)(Bt + (size_t)gc * K + k0 + sseg * 16);
        b0 = gp[0];
        b1 = gp[1];
      }
      *(short8*)&Bs[srow * 40 + sseg * 16] = b0;
      *(short8*)&Bs[srow * 40 + sseg * 16 + 8] = b1;
    }
    __syncthreads();
    half8 af[4], bfv[4];
#pragma unroll
    for (int f = 0; f < 4; f++) {
      af[f] = *(const half8*)&As[(wm * 64 + f * 16 + lm) * 40 + quad * 8];
      bfv[f] = *(const half8*)&Bs[(wn * 64 + f * 16 + lm) * 40 + quad * 8];
    }
#pragma unroll
    for (int i = 0; i < 4; i++)
#pragma unroll
      for (int j = 0; j < 4; j++)
        acc[i][j] = __builtin_amdgcn_mfma_f32_16x16x32_f16(af[i], bfv[j], acc[i][j], 0, 0, 0);
    __syncthreads();
  }
  const bool pb = (*pflag != 0);
#pragma unroll
  for (int i = 0; i < 4; i++) {
#pragma unroll
    for (int j = 0; j < 4; j++) {
      int col = bn + wn * 64 + j * 16 + lm;
      if (col >= N) continue;
#pragma unroll
      for (int r = 0; r < 4; r++) {
        int row = bm + wm * 64 + i * 16 + quad * 4 + r;
        if (row >= M) continue;
        float v = acc[i][j][r];
        if (bias) v += ldf(bias, boff + col, pb);
        if (ACT == 1) v = v > 0.f ? v : 0.f;
        if (OUT == 0)
          ((float*)C)[(size_t)br * Cbs + (size_t)row * N + col] = v;
        else
          ((__half*)C)[(size_t)br * Cbs + (size_t)row * N + col] = __float2half(v);
      }
    }
  }
}

// ---------------- input projection: hn[n][64] fp16 (both branches) ----------------
__global__ __launch_bounds__(256) void proj_nf_kernel(const void* __restrict__ nfA,
                                                      const void* __restrict__ nfB,
                                                      const int* __restrict__ fflag,
                                                      const void* __restrict__ Wn,
                                                      const void* __restrict__ bn,
                                                      const int* __restrict__ pflag,
                                                      __half* __restrict__ hn, int N) {
  __shared__ float Ws[64 * 65];
  __shared__ float bs[64];
  __shared__ float rowbuf[4][64];
  const bool fb = (*fflag != 0), pb = (*pflag != 0);
  const int b = blockIdx.y;
  const void* nf = b ? nfB : nfA;
  size_t woff = (size_t)b * 64 * 64, boff = (size_t)b * 64;
  int t = threadIdx.x;
  for (int i = t; i < 4096; i += 256) {
    int k = i >> 6, c = i & 63;
    Ws[k * 65 + c] = ldf(Wn, woff + i, pb);
  }
  if (t < 64) bs[t] = ldf(bn, boff + t, pb);
  __syncthreads();
  int wave = t >> 6, lane = t & 63;
  int n = blockIdx.x * 4 + wave;
  if (n >= N) return;
  rowbuf[wave][lane] = ldf(nf, (size_t)n * 64 + lane, fb);
  float acc = bs[lane];
#pragma unroll 8
  for (int k = 0; k < 64; k++) acc += rowbuf[wave][k] * Ws[k * 65 + lane];
  hn[(size_t)b * N * 64 + (size_t)n * 64 + lane] = __float2half(acc);
}

// -------- input projection: he in CSR order via ipos (both branches) ----------------
__global__ __launch_bounds__(256) void proj_ef_kernel(const void* __restrict__ efA,
                                                      const void* __restrict__ efB,
                                                      const int* __restrict__ fflag,
                                                      const void* __restrict__ We,
                                                      const void* __restrict__ be,
                                                      const int* __restrict__ pflag,
                                                      const int* __restrict__ ipos,
                                                      __half* __restrict__ he_csr, int E) {
  __shared__ float Ws[16 * 17];
  __shared__ float bs[16];
  __shared__ float efs[16][17];
  const bool fb = (*fflag != 0), pb = (*pflag != 0);
  const int b = blockIdx.y;
  const void* ef = b ? efB : efA;
  size_t woff = (size_t)b * 256, boff = (size_t)b * 16;
  int t = threadIdx.x;
  Ws[(t >> 4) * 17 + (t & 15)] = ldf(We, woff + t, pb);
  if (t < 16) bs[t] = ldf(be, boff + t, pb);
  int el = t >> 4, k = t & 15;
  int e = blockIdx.x * 16 + el;
  float v = 0.f;
  if (e < E) v = ldf(ef, (size_t)e * 16 + k, fb);
  efs[el][k] = v;
  __syncthreads();
  if (e < E) {
    float acc = bs[k];
#pragma unroll
    for (int kk = 0; kk < 16; kk++) acc += efs[el][kk] * Ws[kk * 17 + k];
    int pos = ipos[(size_t)b * E + e];
    he_csr[(size_t)b * E * 16 + (size_t)pos * 16 + k] = __float2half(acc);
  }
}

// ---------------- CSR build (both branches) ----------------
__global__ void count_kernel(const int* __restrict__ dA, const int* __restrict__ dB,
                             int* __restrict__ cnt, int E, int N) {
  int b = blockIdx.y;
  const int* dst = b ? dB : dA;
  int e = blockIdx.x * 256 + threadIdx.x;
  if (e < E) atomicAdd(&cnt[b * N + dst[e]], 1);
}

__global__ void scan1_kernel(const int* __restrict__ cnt, int* __restrict__ incl,
                             int* __restrict__ bsum, int n) {
  __shared__ int buf[256];
  int b = blockIdx.y;
  int t = threadIdx.x;
  int i = blockIdx.x * 256 + t;
  int v = (i < n) ? cnt[b * n + i] : 0;
  buf[t] = v;
  __syncthreads();
  for (int d = 1; d < 256; d <<= 1) {
    int add = (t >= d) ? buf[t - d] : 0;
    __syncthreads();
    buf[t] += add;
    __syncthreads();
  }
  if (i < n) incl[b * n + i] = buf[t];
  if (t == 255) bsum[b * 256 + blockIdx.x] = buf[255];
}

__global__ void scan2_kernel(int* __restrict__ bsum, int nb) {
  __shared__ int buf[256];
  int b = blockIdx.x;
  int t = threadIdx.x;
  int v = (t < nb) ? bsum[b * 256 + t] : 0;
  buf[t] = v;
  __syncthreads();
  for (int d = 1; d < 256; d <<= 1) {
    int add = (t >= d) ? buf[t - d] : 0;
    __syncthreads();
    buf[t] += add;
    __syncthreads();
  }
  if (t < nb) bsum[b * 256 + t] = buf[t] - v;
}

__global__ void scan3_kernel(const int* __restrict__ cnt, const int* __restrict__ incl,
                             const int* __restrict__ bsum, int* __restrict__ offs,
                             int* __restrict__ cursor, int n) {
  int b = blockIdx.y;
  int i = blockIdx.x * 256 + threadIdx.x;
  if (i < n) {
    int e = incl[b * n + i] - cnt[b * n + i] + bsum[b * 256 + blockIdx.x];
    offs[b * (n + 1) + i] = e;
    cursor[b * n + i] = e;
    if (i == n - 1) offs[b * (n + 1) + n] = incl[b * n + i] + bsum[b * 256 + blockIdx.x];
  }
}

__global__ void fill_kernel(const int* __restrict__ dA, const int* __restrict__ dB,
                            int* __restrict__ cursor, int* __restrict__ perm, int E, int N) {
  int b = blockIdx.y;
  const int* dst = b ? dB : dA;
  int e = blockIdx.x * 256 + threadIdx.x;
  if (e < E) {
    int p = atomicAdd(&cursor[b * N + dst[e]], 1);
    perm[(size_t)b * E + p] = e;
  }
}

// ------- sort each node's segment by edge id (LDS scratch), both branches -------------
__global__ __launch_bounds__(64) void sortseg_kernel(const int* __restrict__ off,
                                                     int* __restrict__ perm, int N, int E) {
  __shared__ int loc[64 * 64];
  int b = blockIdx.y;
  const int* offb = off + b * (N + 1);
  int* permb = perm + (size_t)b * E;
  int t = threadIdx.x;
  int n = blockIdx.x * 64 + t;
  if (n >= N) return;
  int e0 = offb[n], e1 = offb[n + 1];
  int d = e1 - e0;
  if (d <= 1) return;
  if (d <= 64) {
    for (int i = 0; i < d; i++) loc[i * 64 + t] = permb[e0 + i];
    for (int i = 1; i < d; i++) {
      int v = loc[i * 64 + t];
      int j = i - 1;
      while (j >= 0 && loc[j * 64 + t] > v) { loc[(j + 1) * 64 + t] = loc[j * 64 + t]; j--; }
      loc[(j + 1) * 64 + t] = v;
    }
    for (int i = 0; i < d; i++) permb[e0 + i] = loc[i * 64 + t];
  } else {
    for (int i = 0; i < d - 1; i++) {
      int mi = i;
      for (int j = i + 1; j < d; j++)
        if (permb[e0 + j] < permb[e0 + mi]) mi = j;
      int tmp = permb[e0 + i];
      permb[e0 + i] = permb[e0 + mi];
      permb[e0 + mi] = tmp;
    }
  }
}

// -------- src_csr[i] = src[perm[i]]; ipos[perm[i]] = i (both branches) ----------------
__global__ void srccsr_kernel(const int* __restrict__ sA, const int* __restrict__ sB,
                              const int* __restrict__ perm, int* __restrict__ src_csr,
                              int* __restrict__ ipos, int E) {
  int b = blockIdx.y;
  const int* src = b ? sB : sA;
  int i = blockIdx.x * 256 + threadIdx.x;
  if (i < E) {
    int e = perm[(size_t)b * E + i];
    src_csr[(size_t)b * E + i] = src[e];
    ipos[(size_t)b * E + e] = i;
  }
}

// ------- EdgeGraphConv: wave-per-node; hn uint loads 2 edges/step, he_csr sequential ---
__global__ __launch_bounds__(256) void edgeconv_kernel(const int* __restrict__ off,
                                                       const int* __restrict__ src_csr,
                                                       const __half* __restrict__ hn,
                                                       const __half* __restrict__ he_csr,
                                                       __half* __restrict__ xsum, int N, int E) {
  int b = blockIdx.y;
  const int* offb = off + b * (N + 1);
  const int* scb = src_csr + (size_t)b * E;
  const unsigned* hnu = (const unsigned*)(hn + (size_t)b * N * 64);
  const __half* heb = he_csr + (size_t)b * E * 16;
  int wave = threadIdx.x >> 6, lane = threadIdx.x & 63;
  int n = blockIdx.x * 4 + wave;
  if (n >= N) return;
  int e0 = offb[n], e1 = offb[n + 1];
  int hl = lane & 31, pr = lane >> 5;  // half-lane (feature pair), parity (edge)
  float ax = 0.f, ay = 0.f;
  int eg = e0;
  // 8 edges per iter: each half-wave takes 4 (even/odd interleave), 4 uint loads in flight
  for (; eg + 8 <= e1; eg += 8) {
    int ea = eg + pr;
    int s0 = scb[ea], s1 = scb[ea + 2], s2 = scb[ea + 4], s3 = scb[ea + 6];
    unsigned w0 = hnu[(size_t)s0 * 32 + hl];
    unsigned w1 = hnu[(size_t)s1 * 32 + hl];
    unsigned w2 = hnu[(size_t)s2 * 32 + hl];
    unsigned w3 = hnu[(size_t)s3 * 32 + hl];
    float2 f0 = __half22float2(*(__half2*)&w0);
    float2 f1 = __half22float2(*(__half2*)&w1);
    float2 f2 = __half22float2(*(__half2*)&w2);
    float2 f3 = __half22float2(*(__half2*)&w3);
    ax += f0.x; ay += f0.y;
    ax += f1.x; ay += f1.y;
    ax += f2.x; ay += f2.y;
    ax += f3.x; ay += f3.y;
  }
  for (; eg + 2 <= e1; eg += 2) {
    int s0 = scb[eg + pr];
    unsigned w0 = hnu[(size_t)s0 * 32 + hl];
    float2 f0 = __half22float2(*(__half2*)&w0);
    ax += f0.x; ay += f0.y;
  }
  if (eg < e1 && pr == 0) {
    int s0 = scb[eg];
    unsigned w0 = hnu[(size_t)s0 * 32 + hl];
    float2 f0 = __half22float2(*(__half2*)&w0);
    ax += f0.x; ay += f0.y;
  }
  // combine even/odd halves
  ax += __shfl_xor(ax, 32);
  ay += __shfl_xor(ay, 32);
  // he part: lane = grp*16+f; grp strides edges; sequential he_csr reads
  int grp = lane >> 4, f = lane & 15;
  float hacc = 0.f;
  for (int e = e0 + grp; e < e1; e += 4) hacc += __half2float(heb[(size_t)e * 16 + f]);
  hacc += __shfl_xor(hacc, 16);
  hacc += __shfl_xor(hacc, 32);
  __half* xr = xsum + (size_t)b * N * 80 + (size_t)n * 80;
  if (lane < 32) {
    __half2 h2;
    h2.x = __float2half(ax);
    h2.y = __float2half(ay);
    *(__half2*)&xr[hl * 2] = h2;
  }
  if (lane < 16) xr[64 + lane] = __float2half(hacc);
}

// ---------------- attention el/er (both branches) ----------------
__global__ __launch_bounds__(256) void attn_lr_kernel(const __half* __restrict__ z,
                                                      const void* __restrict__ al,
                                                      const void* __restrict__ ar, size_t astr,
                                                      const int* __restrict__ pflag,
                                                      float* __restrict__ el,
                                                      float* __restrict__ er, int N) {
  const bool pb = (*pflag != 0);
  const int b = blockIdx.y;
  const size_t off = (size_t)b * astr;
  const __half* zb = z + (size_t)b * N * 512;
  int n = (blockIdx.x * blockDim.x + threadIdx.x) >> 6;
  int lane = threadIdx.x & 63;
  if (n >= N) return;
  union { uint4 q; __half s[8]; } u;
  u.q = *(const uint4*)(zb + (size_t)n * 512 + lane * 8);
  float sl = 0.f, sr = 0.f;
#pragma unroll
  for (int q = 0; q < 8; q++) {
    int idx = lane * 8 + q;
    float zv = __half2float(u.s[q]);
    sl += zv * ldf(al, off + idx, pb);
    sr += zv * ldf(ar, off + idx, pb);
  }
#pragma unroll
  for (int o = 1; o < 16; o <<= 1) {
    sl += __shfl_xor(sl, o);
    sr += __shfl_xor(sr, o);
  }
  if ((lane & 15) == 0) {
    int h = lane >> 4;
    el[(size_t)b * N * 4 + n * 4 + h] = sl;
    er[(size_t)b * N * 4 + n * 4 + h] = sr;
  }
}

// ------- per-node attn exp in CSR order + denominator (both branches) -----------------
__global__ void attn_sden_kernel(const int* __restrict__ off, const int* __restrict__ src_csr,
                                 const float* __restrict__ el, const float* __restrict__ er,
                                 float* __restrict__ ecsr, float* __restrict__ sden, int N, int E) {
  int b = blockIdx.y;
  const int* offb = off + b * (N + 1);
  const int* scb = src_csr + (size_t)b * E;
  const float* elb = el + (size_t)b * N * 4;
  float* ecb = ecsr + (size_t)b * E * 4;
  int idx = blockIdx.x * 256 + threadIdx.x;
  int n = idx >> 2, h = idx & 3;
  if (n >= N) return;
  int e0 = offb[n], e1 = offb[n + 1];
  float ern = er[(size_t)b * N * 4 + n * 4 + h];
  float s = 0.f;
  for (int eg = e0; eg < e1; eg++) {
    float v = elb[scb[eg] * 4 + h] + ern;
    v = v > 0.f ? v : 0.2f * v;
    v = fminf(v, 60.f);
    float ev = expf(v);
    ecb[eg * 4 + h] = ev;
    s += ev;
  }
  sden[(size_t)b * N * 4 + n * 4 + h] = s;
}

// ---------------- lean GAT gather (both branches), 8-way ILP, fp16 out ----------------
__global__ __launch_bounds__(256) void gat_gather_kernel(const int* __restrict__ off,
                                                         const int* __restrict__ src_csr,
                                                         const __half* __restrict__ z,
                                                         const float* __restrict__ ecsr,
                                                         const float* __restrict__ sden,
                                                         const void* __restrict__ gb, size_t gstr,
                                                         const int* __restrict__ pflag,
                                                         __half* __restrict__ out, int N, int E) {
  const bool pb = (*pflag != 0);
  int b = blockIdx.y;
  const int* offb = off + b * (N + 1);
  const int* scb = src_csr + (size_t)b * E;
  const __half* zb = z + (size_t)b * N * 512;
  const float* ecb = ecsr + (size_t)b * E * 4;
  const size_t goff = (size_t)b * gstr;
  int n = (blockIdx.x * blockDim.x + threadIdx.x) >> 6;
  int lane = threadIdx.x & 63;
  if (n >= N) return;
  int h = lane >> 4;
  float sd = sden[(size_t)b * N * 4 + n * 4 + h];
  float sinv = sd > 0.f ? 1.f / sd : 0.f;
  float acc[8] = {0.f, 0.f, 0.f, 0.f, 0.f, 0.f, 0.f, 0.f};
  int e0 = offb[n], e1 = offb[n + 1];
  int eg = e0;
  for (; eg + 8 <= e1; eg += 8) {
    int s[8];
    float a[8];
#pragma unroll
    for (int u = 0; u < 8; u++) {
      s[u] = scb[eg + u];
      a[u] = ecb[(eg + u) * 4 + h] * sinv;
    }
    union { uint4 q; __half s[8]; } uu[8];
#pragma unroll
    for (int u = 0; u < 8; u++)
      uu[u].q = *(const uint4*)(zb + (size_t)s[u] * 512 + lane * 8);
#pragma unroll
    for (int u = 0; u < 8; u++)
#pragma unroll
      for (int q = 0; q < 8; q++) acc[q] += a[u] * __half2float(uu[u].s[q]);
  }
  for (; eg < e1; eg++) {
    int s0 = scb[eg];
    float a0 = ecb[eg * 4 + h] * sinv;
    union { uint4 q; __half s[8]; } u0;
    u0.q = *(const uint4*)(zb + (size_t)s0 * 512 + lane * 8);
#pragma unroll
    for (int q = 0; q < 8; q++) acc[q] += a0 * __half2float(u0.s[q]);
  }
  union { uint4 q; __half s[8]; } w;
#pragma unroll
  for (int q = 0; q < 8; q++) {
    float v = acc[q] + ldf(gb, goff + lane * 8 + q, pb);
    w.s[q] = __float2half(v > 0.f ? v : 0.01f * v);
  }
  *(uint4*)(out + (size_t)b * N * 512 + (size_t)n * 512 + lane * 8) = w.q;
}

// ---------------- node weight (both branches) ----------------
__global__ __launch_bounds__(256) void wnode_kernel(const float* __restrict__ x,
                                                    const void* __restrict__ wsw,
                                                    const void* __restrict__ wsb,
                                                    const int* __restrict__ pflag,
                                                    float* __restrict__ w, int N) {
  const bool pb = (*pflag != 0);
  int b = blockIdx.y;
  const float* xb = x + (size_t)b * N * 128;
  size_t woff = (size_t)b * 128, boff = (size_t)b;
  int n = (blockIdx.x * blockDim.x + threadIdx.x) >> 6;
  int lane = threadIdx.x & 63;
  if (n >= N) return;
  float s = xb[(size_t)n * 128 + lane] * ldf(wsw, woff + lane, pb) +
            xb[(size_t)n * 128 + 64 + lane] * ldf(wsw, woff + 64 + lane, pb);
#pragma unroll
  for (int o = 1; o < 64; o <<= 1) s += __shfl_xor(s, o);
  if (lane == 0) {
    float t = s + ldf(wsb, boff, pb);
    t = fmaxf(fminf(t, 60.f), -60.f);
    w[(size_t)b * N + n] = 1.f / (1.f + expf(-t));
  }
}

__device__ __forceinline__ int lower_bound_dev(const int* a, int n, int v) {
  int lo = 0, hi = n;
  while (lo < hi) {
    int mid = (lo + hi) >> 1;
    if (a[mid] < v) lo = mid + 1; else hi = mid;
  }
  return lo;
}

// ---------------- readout phase 1 (both branches) ----------------
__global__ __launch_bounds__(128) void readout_p1_kernel(const float* __restrict__ x,
                                                         const float* __restrict__ w,
                                                         const int* __restrict__ gidA,
                                                         const int* __restrict__ gidB, int N,
                                                         double* __restrict__ psum,
                                                         float* __restrict__ pmax) {
  int b = blockIdx.y;
  const int* gid = b ? gidB : gidA;
  const float* xb = x + (size_t)b * N * 128;
  const float* wb = w + (size_t)b * N;
  int g = blockIdx.x >> 4;
  int c = blockIdx.x & 15;
  int d = threadIdx.x;
  __shared__ int ss, se;
  if (d == 0) {
    ss = lower_bound_dev(gid, N, g);
    se = lower_bound_dev(gid, N, g + 1);
  }
  __syncthreads();
  int len = se - ss;
  int a = ss + (int)(((long)len * c) >> 4);
  int bb = ss + (int)(((long)len * (c + 1)) >> 4);
  double s = 0.0;
  float m = -1e30f;
  for (int n = a; n < bb; n++) {
    float v = xb[(size_t)n * 128 + d];
    s += (double)v * (double)wb[n];
    m = fmaxf(m, v);
  }
  psum[((size_t)b * Bg * 16 + blockIdx.x) * 128 + d] = s;
  pmax[((size_t)b * Bg * 16 + blockIdx.x) * 128 + d] = m;
}

// ---------------- readout phase 2 (both branches) ----------------
__global__ __launch_bounds__(128) void readout_p2_kernel(const double* __restrict__ psum,
                                                         const float* __restrict__ pmax,
                                                         float* __restrict__ hs,
                                                         float* __restrict__ hm) {
  int b = blockIdx.y;
  int g = blockIdx.x, d = threadIdx.x;
  double s = 0.0;
  float m = -1e30f;
#pragma unroll
  for (int c = 0; c < 16; c++) {
    s += psum[((size_t)b * Bg * 16 + g * 16 + c) * 128 + d];
    m = fmaxf(m, pmax[((size_t)b * Bg * 16 + g * 16 + c) * 128 + d]);
  }
  hs[(size_t)b * Bg * 128 + g * 128 + d] = (float)s;
  hm[(size_t)b * Bg * 128 + g * 128 + d] = m;
}

// ---------------- pool linear (both branches) ----------------
__global__ __launch_bounds__(128) void pool_kernel(const float* __restrict__ hs,
                                                   const float* __restrict__ hm,
                                                   const void* __restrict__ Wp,
                                                   const void* __restrict__ bp,
                                                   const int* __restrict__ pflag,
                                                   float* __restrict__ bout) {
  const bool pb = (*pflag != 0);
  int b = blockIdx.y;
  size_t woff = (size_t)b * 256 * 128, boff = (size_t)b * 128;
  int g = blockIdx.x, j = threadIdx.x;
  __shared__ float hg[256];
  hg[j] = hs[(size_t)b * Bg * 128 + g * 128 + j];
  hg[128 + j] = hm[(size_t)b * Bg * 128 + g * 128 + j];
  __syncthreads();
  double acc = (double)ldf(bp, boff + j, pb);
  for (int k = 0; k < 256; k++) acc += (double)hg[k] * (double)ldf(Wp, woff + (size_t)k * 128 + j, pb);
  bout[(size_t)b * Bg * 128 + g * 128 + j] = (float)acc;
}

// ---------------- final head ----------------
__global__ __launch_bounds__(128) void head_kernel(const float* __restrict__ bA,
                                                   const float* __restrict__ bB,
                                                   const void* __restrict__ Wo1,
                                                   const void* __restrict__ bo1,
                                                   const void* __restrict__ Wo2,
                                                   const void* __restrict__ bo2,
                                                   const int* __restrict__ pflag,
                                                   const int* __restrict__ oflag,
                                                   void* __restrict__ out) {
  const bool pb = (*pflag != 0);
  int g = blockIdx.x, j = threadIdx.x;
  __shared__ float zr[256];
  __shared__ double t[128];
  zr[j] = bA[g * 128 + j];
  zr[128 + j] = bB[g * 128 + j];
  __syncthreads();
  double acc = (double)ldf(bo1, j, pb);
  for (int k = 0; k < 256; k++) acc += (double)zr[k] * (double)ldf(Wo1, (size_t)k * 128 + j, pb);
  if (acc < 0.0) acc *= 0.01;
  t[j] = acc * (double)ldf(Wo2, j, pb);
  __syncthreads();
  for (int sdt = 64; sdt > 0; sdt >>= 1) {
    if (j < sdt) t[j] += t[j + sdt];
    __syncthreads();
  }
  if (j == 0) {
    float v = (float)(t[0] + (double)ldf(bo2, 0, pb));
    if (*oflag) ((bf16*)out)[g] = __float2bfloat16(v);
    else ((float*)out)[g] = v;
  }
}

extern "C" void kernel_launch(void* const* d_in, const int* in_sizes, int n_in,
                              void* d_out, int out_size, void* d_ws, size_t ws_size,
                              hipStream_t stream) {
  const int* srcA = (const int*)d_in[0];
  const int* dstA = (const int*)d_in[1];
  const int* gidA = (const int*)d_in[2];
  const void* nfA = d_in[3];
  const void* efA = d_in[4];
  const int* srcB = (const int*)d_in[5];
  const int* dstB = (const int*)d_in[6];
  const int* gidB = (const int*)d_in[7];
  const void* nfB = d_in[8];
  const void* efB = d_in[9];
  const void* p_Wn = d_in[10];
  const void* p_bn = d_in[11];
  const void* p_We = d_in[12];
  const void* p_be = d_in[13];
  const void* p_Wc = d_in[14];
  const void* p_bc = d_in[15];
  const void* p_fc1 = d_in[16];
  const void* p_al1 = d_in[17];
  const void* p_ar1 = d_in[18];
  const void* p_gb1 = d_in[19];
  const void* p_Wl1 = d_in[20];
  const void* p_bl1 = d_in[21];
  const void* p_fc2 = d_in[22];
  const void* p_al2 = d_in[23];
  const void* p_ar2 = d_in[24];
  const void* p_gb2 = d_in[25];
  const void* p_Wl2 = d_in[26];
  const void* p_bl2 = d_in[27];
  const void* p_ws_w = d_in[28];
  const void* p_ws_b = d_in[29];
  const void* p_Wp = d_in[30];
  const void* p_bp = d_in[31];
  const void* Wo1 = d_in[32];
  const void* bo1 = d_in[33];
  const void* Wo2 = d_in[34];
  const void* bo2 = d_in[35];

  // workspace carve-up (~146 MB)
  char* wp = (char*)d_ws;
  auto alloc = [&](size_t bytes) -> char* {
    char* p = wp;
    wp += (bytes + 255) & ~(size_t)255;
    return p;
  };
  int* flags = (int*)alloc(2 * 4);
  int* cnt = (int*)alloc((size_t)2 * Nn * 4);
  int* incl = (int*)alloc((size_t)2 * Nn * 4);
  int* bsum = (int*)alloc(2 * 256 * 4);
  int* offs = (int*)alloc((size_t)2 * (Nn + 1) * 4);
  int* cursor = (int*)alloc((size_t)2 * Nn * 4);
  int* perm = (int*)alloc((size_t)2 * Ne * 4);
  int* src_csr = (int*)alloc((size_t)2 * Ne * 4);
  int* ipos = (int*)alloc((size_t)2 * Ne * 4);
  float* ecsr = (float*)alloc((size_t)2 * Ne * 4 * 4);
  float* sden = (float*)alloc((size_t)2 * Nn * 4 * 4);
  float* el = (float*)alloc((size_t)2 * Nn * 4 * 4);
  float* er = (float*)alloc((size_t)2 * Nn * 4 * 4);
  float* wn = (float*)alloc((size_t)2 * Nn * 4);
  double* psum = (double*)alloc((size_t)2 * Bg * 16 * 128 * 8);
  float* pmax = (float*)alloc((size_t)2 * Bg * 16 * 128 * 4);
  float* hsb = (float*)alloc((size_t)2 * Bg * 128 * 4);
  float* hmb = (float*)alloc((size_t)2 * Bg * 128 * 4);
  float* bout = (float*)alloc((size_t)2 * Bg * 128 * 4);
  // transposed fp16 weight planes
  __half* Wct = (__half*)alloc((size_t)2 * 80 * 80 * 2);
  __half* fc1t = (__half*)alloc((size_t)2 * 512 * 80 * 2);
  __half* Wl1t = (__half*)alloc((size_t)2 * 128 * 512 * 2);
  __half* fc2t = (__half*)alloc((size_t)2 * 512 * 128 * 2);
  __half* Wl2t = (__half*)alloc((size_t)2 * 128 * 512 * 2);
  // big overlaid regions
  char* R = alloc((size_t)2 * Nn * 512 * 2);   // he_csr+hn early -> z -> x2
  char* H = alloc((size_t)2 * Nn * 512 * 2);   // xsum early -> hb
  __half* xcx1 = (__half*)alloc((size_t)2 * Nn * 128 * 2);
  // overlays
  __half* he_csr = (__half*)R;
  __half* hn = (__half*)(R + (size_t)2 * Ne * 16 * 2);
  __half* z = (__half*)R;
  float* x2 = (float*)R;
  __half* xsum = (__half*)H;
  __half* hb = (__half*)H;
  __half* xc = xcx1;
  __half* x1 = xcx1;

  auto cdiv = [](int a, int b) { return (a + b - 1) / b; };

  detect_kernel<<<1, 256, 0, stream>>>((const u16*)nfA, 8192, (const u16*)p_fc1, 8192, flags);
  int* fflag = &flags[0];
  int* pflag = &flags[1];

  // prep: fused transpose+convert of all fp16 weight planes (both branches)
  {
    TCAll tc;
    int segK[5] = {80, 80, 512, 128, 512};
    int segN[5] = {80, 512, 128, 512, 128};
    const void* segW[5] = {p_Wc, p_fc1, p_Wl1, p_fc2, p_Wl2};
    __half* segH[5] = {Wct, fc1t, Wl1t, fc2t, Wl2t};
    int start = 0, s = 0;
    for (int i = 0; i < 2; i++)
      for (int m = 0; m < 5; m++) {
        int sz = segK[m] * segN[m];
        tc.t[s].W = segW[m];
        tc.t[s].off = (size_t)i * sz;
        tc.t[s].H = segH[m] + (size_t)i * sz;
        tc.t[s].K = segK[m];
        tc.t[s].N = segN[m];
        tc.t[s].start = start;
        start += sz;
        s++;
      }
    tc.total = start;
    transconv_all_kernel<<<cdiv(start, 256), 256, 0, stream>>>(tc, pflag);
  }

  const int nb = cdiv(Nn, 256);

  // ---- merged front-end (both branches in every dispatch) ----
  hipMemsetAsync(cnt, 0, (size_t)2 * Nn * 4, stream);
  count_kernel<<<dim3(cdiv(Ne, 256), 2), 256, 0, stream>>>(dstA, dstB, cnt, Ne, Nn);
  scan1_kernel<<<dim3(nb, 2), 256, 0, stream>>>(cnt, incl, bsum, Nn);
  scan2_kernel<<<2, 256, 0, stream>>>(bsum, nb);
  scan3_kernel<<<dim3(nb, 2), 256, 0, stream>>>(cnt, incl, bsum, offs, cursor, Nn);
  fill_kernel<<<dim3(cdiv(Ne, 256), 2), 256, 0, stream>>>(dstA, dstB, cursor, perm, Ne, Nn);
  sortseg_kernel<<<dim3(cdiv(Nn, 64), 2), 64, 0, stream>>>(offs, perm, Nn, Ne);
  srccsr_kernel<<<dim3(cdiv(Ne, 256), 2), 256, 0, stream>>>(srcA, srcB, perm, src_csr, ipos, Ne);
  proj_nf_kernel<<<dim3(cdiv(Nn, 4), 2), 256, 0, stream>>>(
      nfA, nfB, fflag, p_Wn, p_bn, pflag, hn, Nn);
  proj_ef_kernel<<<dim3(cdiv(Ne, 16), 2), 256, 0, stream>>>(
      efA, efB, fflag, p_We, p_be, pflag, ipos, he_csr, Ne);
  edgeconv_kernel<<<dim3(cdiv(Nn, 4), 2), 256, 0, stream>>>(
      offs, src_csr, hn, he_csr, xsum, Nn, Ne);

  const int gm = cdiv(Nn, 128);

  // ---- main pipeline, both branches per dispatch ----
  mfma_f16_gemm<1, 2><<<dim3(gm, 1, 2), 256, 0, stream>>>(
      xsum, (size_t)Nn * 80, Wct, 6400, p_bc, 80, pflag, xc, (size_t)Nn * 80, Nn, 80, 80);
  // GAT 1
  mfma_f16_gemm<0, 2><<<dim3(gm, 4, 2), 256, 0, stream>>>(
      xc, (size_t)Nn * 80, fc1t, (size_t)512 * 80, nullptr, 0, pflag, z, (size_t)Nn * 512,
      Nn, 80, 512);
  attn_lr_kernel<<<dim3(cdiv(Nn * 64, 256), 2), 256, 0, stream>>>(
      z, p_al1, p_ar1, 512, pflag, el, er, Nn);
  attn_sden_kernel<<<dim3(cdiv(Nn * 4, 256), 2), 256, 0, stream>>>(
      offs, src_csr, el, er, ecsr, sden, Nn, Ne);
  gat_gather_kernel<<<dim3(cdiv(Nn * 64, 256), 2), 256, 0, stream>>>(
      offs, src_csr, z, ecsr, sden, p_gb1, 512, pflag, hb, Nn, Ne);
  mfma_f16_gemm<0, 2><<<dim3(gm, 1, 2), 256, 0, stream>>>(
      hb, (size_t)Nn * 512, Wl1t, (size_t)128 * 512, p_bl1, 128, pflag, x1, (size_t)Nn * 128,
      Nn, 512, 128);
  // GAT 2
  mfma_f16_gemm<0, 2><<<dim3(gm, 4, 2), 256, 0, stream>>>(
      x1, (size_t)Nn * 128, fc2t, (size_t)512 * 128, nullptr, 0, pflag, z, (size_t)Nn * 512,
      Nn, 128, 512);
  attn_lr_kernel<<<dim3(cdiv(Nn * 64, 256), 2), 256, 0, stream>>>(
      z, p_al2, p_ar2, 512, pflag, el, er, Nn);
  attn_sden_kernel<<<dim3(cdiv(Nn * 4, 256), 2), 256, 0, stream>>>(
      offs, src_csr, el, er, ecsr, sden, Nn, Ne);
  gat_gather_kernel<<<dim3(cdiv(Nn * 64, 256), 2), 256, 0, stream>>>(
      offs, src_csr, z, ecsr, sden, p_gb2, 512, pflag, hb, Nn, Ne);
  mfma_f16_gemm<0, 0><<<dim3(gm, 1, 2), 256, 0, stream>>>(
      hb, (size_t)Nn * 512, Wl2t, (size_t)128 * 512, p_bl2, 128, pflag, x2, (size_t)Nn * 128,
      Nn, 512, 128);
  // readout
  wnode_kernel<<<dim3(cdiv(Nn * 64, 256), 2), 256, 0, stream>>>(
      x2, p_ws_w, p_ws_b, pflag, wn, Nn);
  readout_p1_kernel<<<dim3(Bg * 16, 2), 128, 0, stream>>>(x2, wn, gidA, gidB, Nn, psum, pmax);
  readout_p2_kernel<<<dim3(Bg, 2), 128, 0, stream>>>(psum, pmax, hsb, hmb);
  pool_kernel<<<dim3(Bg, 2), 128, 0, stream>>>(hsb, hmb, p_Wp, p_bp, pflag, bout);

  head_kernel<<<Bg, 128, 0, stream>>>(bout, bout + (size_t)Bg * 128, Wo1, bo1, Wo2, bo2,
                                      pflag, fflag, d_out);
}

// Round 12
// 1113.524 us; speedup vs baseline: 1.0301x; 1.0301x over previous
//
#include <hip/hip_runtime.h>
#include <hip/hip_bf16.h>
#include <hip/hip_fp16.h>

typedef __hip_bfloat16 bf16;
typedef unsigned short u16;
typedef __attribute__((ext_vector_type(8))) short short8;
typedef __attribute__((ext_vector_type(4))) float floatx4;
typedef _Float16 half8 __attribute__((ext_vector_type(8)));

static constexpr int Nn = 25000;   // nodes
static constexpr int Ne = 400000;  // edges
static constexpr int Bg = 64;      // graphs

__device__ __forceinline__ float ldf(const void* p, size_t i, bool b16) {
  return b16 ? __bfloat162float(((const bf16*)p)[i]) : ((const float*)p)[i];
}

// ---------------- dtype detection ----------------
__global__ void detect_kernel(const u16* a, int n, const u16* b, int m, int* flags) {
  __shared__ int c0, c1;
  if (threadIdx.x == 0) { c0 = 0; c1 = 0; }
  __syncthreads();
  int t = threadIdx.x;
  int l0 = 0, l1 = 0;
  for (int i = t; i < n; i += 256) {
    unsigned e = (a[i] >> 7) & 0xFF;
    if (e >= 140) l0++;
  }
  for (int i = t; i < m; i += 256) {
    unsigned e = (b[i] >> 7) & 0xFF;
    if (e >= 140) l1++;
  }
  atomicAdd(&c0, l0);
  atomicAdd(&c1, l1);
  __syncthreads();
  if (t == 0) {
    flags[0] = (c0 < n / 16) ? 1 : 0;
    flags[1] = (c1 < m / 16) ? 1 : 0;
  }
}

// ------- fused transpose+convert: all big weights -> fp16 plane [N][K] ----------------
struct TC { const void* W; size_t off; __half* H; int K; int N; int start; };
struct TCAll { TC t[10]; int total; };

__global__ void transconv_all_kernel(TCAll a, const int* __restrict__ pflag) {
  const bool pb = (*pflag != 0);
  int idx = blockIdx.x * 256 + threadIdx.x;
  if (idx >= a.total) return;
  int s = 0;
  while (s + 1 < 10 && idx >= a.t[s + 1].start) s++;
  int li = idx - a.t[s].start;
  int K = a.t[s].K, N = a.t[s].N;
  int k = li / N, n = li - k * N;
  float w = ldf(a.t[s].W, a.t[s].off + li, pb);
  a.t[s].H[(size_t)n * K + k] = __float2half(w);
}

// ---------------- fp16 MFMA GEMM (branch dim = blockIdx.z) ----------------
template <int ACT, int OUT>
__global__ __launch_bounds__(256) void mfma_f16_gemm(const __half* __restrict__ A, size_t Abs,
                                                     const __half* __restrict__ Bt, size_t Bbs,
                                                     const void* __restrict__ bias, size_t bstr,
                                                     const int* __restrict__ pflag,
                                                     void* __restrict__ C, size_t Cbs,
                                                     int M, int K, int N) {
  const int br = blockIdx.z;
  A += (size_t)br * Abs;
  Bt += (size_t)br * Bbs;
  const size_t boff = (size_t)br * bstr;
  __shared__ short As[128 * 40];
  __shared__ short Bs[128 * 40];
  const int bm = blockIdx.x * 128;
  const int bn = blockIdx.y * 128;
  const int tid = threadIdx.x;
  const int lane = tid & 63;
  const int wave = tid >> 6;
  const int wm = wave >> 1, wn = wave & 1;
  const int lm = lane & 15, quad = lane >> 4;
  const int srow = tid >> 1;
  const int sseg = tid & 1;
  floatx4 acc[4][4] = {};
  for (int k0 = 0; k0 < K; k0 += 32) {
    bool kv = (k0 + sseg * 16) < K;
    {
      int gr = bm + srow;
      short8 a0 = {}, a1 = {};
      if (gr < M && kv) {
        const short8* gp = (const short8*)(A + (size_t)gr * K + k0 + sseg * 16);
        a0 = gp[0];
        a1 = gp[1];
      }
      *(short8*)&As[srow * 40 + sseg * 16] = a0;
      *(short8*)&As[srow * 40 + sseg * 16 + 8] = a1;
    }
    {
      int gc = bn + srow;
      short8 b0 = {}, b1 = {};
      if (gc < N && kv) {
        const short8* gp = (const short8*)(Bt + (size_t)gc * K + k0 + sseg * 16);
        b0 = gp[0];
        b1 = gp[1];
      }
      *(short8*)&Bs[srow * 40 + sseg * 16] = b0;
      *(short8*)&Bs[srow * 40 + sseg * 16 + 8] = b1;
    }
    __syncthreads();
    half8 af[4], bfv[4];
#pragma unroll
    for (int f = 0; f < 4; f++) {
      af[f] = *(const half8*)&As[(wm * 64 + f * 16 + lm) * 40 + quad * 8];
      bfv[f] = *(const half8*)&Bs[(wn * 64 + f * 16 + lm) * 40 + quad * 8];
    }
#pragma unroll
    for (int i = 0; i < 4; i++)
#pragma unroll
      for (int j = 0; j < 4; j++)
        acc[i][j] = __builtin_amdgcn_mfma_f32_16x16x32_f16(af[i], bfv[j], acc[i][j], 0, 0, 0);
    __syncthreads();
  }
  const bool pb = (*pflag != 0);
#pragma unroll
  for (int i = 0; i < 4; i++) {
#pragma unroll
    for (int j = 0; j < 4; j++) {
      int col = bn + wn * 64 + j * 16 + lm;
      if (col >= N) continue;
#pragma unroll
      for (int r = 0; r < 4; r++) {
        int row = bm + wm * 64 + i * 16 + quad * 4 + r;
        if (row >= M) continue;
        float v = acc[i][j][r];
        if (bias) v += ldf(bias, boff + col, pb);
        if (ACT == 1) v = v > 0.f ? v : 0.f;
        if (OUT == 0)
          ((float*)C)[(size_t)br * Cbs + (size_t)row * N + col] = v;
        else
          ((__half*)C)[(size_t)br * Cbs + (size_t)row * N + col] = __float2half(v);
      }
    }
  }
}

// ---------------- input projection: hn[n][64] fp16 (both branches) ----------------
__global__ __launch_bounds__(256) void proj_nf_kernel(const void* __restrict__ nfA,
                                                      const void* __restrict__ nfB,
                                                      const int* __restrict__ fflag,
                                                      const void* __restrict__ Wn,
                                                      const void* __restrict__ bn,
                                                      const int* __restrict__ pflag,
                                                      __half* __restrict__ hn, int N) {
  __shared__ float Ws[64 * 65];
  __shared__ float bs[64];
  __shared__ float rowbuf[4][64];
  const bool fb = (*fflag != 0), pb = (*pflag != 0);
  const int b = blockIdx.y;
  const void* nf = b ? nfB : nfA;
  size_t woff = (size_t)b * 64 * 64, boff = (size_t)b * 64;
  int t = threadIdx.x;
  for (int i = t; i < 4096; i += 256) {
    int k = i >> 6, c = i & 63;
    Ws[k * 65 + c] = ldf(Wn, woff + i, pb);
  }
  if (t < 64) bs[t] = ldf(bn, boff + t, pb);
  __syncthreads();
  int wave = t >> 6, lane = t & 63;
  int n = blockIdx.x * 4 + wave;
  if (n >= N) return;
  rowbuf[wave][lane] = ldf(nf, (size_t)n * 64 + lane, fb);
  float acc = bs[lane];
#pragma unroll 8
  for (int k = 0; k < 64; k++) acc += rowbuf[wave][k] * Ws[k * 65 + lane];
  hn[(size_t)b * N * 64 + (size_t)n * 64 + lane] = __float2half(acc);
}

// -------- input projection: he in CSR order via ipos (both branches) ----------------
__global__ __launch_bounds__(256) void proj_ef_kernel(const void* __restrict__ efA,
                                                      const void* __restrict__ efB,
                                                      const int* __restrict__ fflag,
                                                      const void* __restrict__ We,
                                                      const void* __restrict__ be,
                                                      const int* __restrict__ pflag,
                                                      const int* __restrict__ ipos,
                                                      __half* __restrict__ he_csr, int E) {
  __shared__ float Ws[16 * 17];
  __shared__ float bs[16];
  __shared__ float efs[16][17];
  const bool fb = (*fflag != 0), pb = (*pflag != 0);
  const int b = blockIdx.y;
  const void* ef = b ? efB : efA;
  size_t woff = (size_t)b * 256, boff = (size_t)b * 16;
  int t = threadIdx.x;
  Ws[(t >> 4) * 17 + (t & 15)] = ldf(We, woff + t, pb);
  if (t < 16) bs[t] = ldf(be, boff + t, pb);
  int el = t >> 4, k = t & 15;
  int e = blockIdx.x * 16 + el;
  float v = 0.f;
  if (e < E) v = ldf(ef, (size_t)e * 16 + k, fb);
  efs[el][k] = v;
  __syncthreads();
  if (e < E) {
    float acc = bs[k];
#pragma unroll
    for (int kk = 0; kk < 16; kk++) acc += efs[el][kk] * Ws[kk * 17 + k];
    int pos = ipos[(size_t)b * E + e];
    he_csr[(size_t)b * E * 16 + (size_t)pos * 16 + k] = __float2half(acc);
  }
}

// ---------------- CSR build (both branches) ----------------
__global__ void count_kernel(const int* __restrict__ dA, const int* __restrict__ dB,
                             int* __restrict__ cnt, int E, int N) {
  int b = blockIdx.y;
  const int* dst = b ? dB : dA;
  int e = blockIdx.x * 256 + threadIdx.x;
  if (e < E) atomicAdd(&cnt[b * N + dst[e]], 1);
}

__global__ void scan1_kernel(const int* __restrict__ cnt, int* __restrict__ incl,
                             int* __restrict__ bsum, int n) {
  __shared__ int buf[256];
  int b = blockIdx.y;
  int t = threadIdx.x;
  int i = blockIdx.x * 256 + t;
  int v = (i < n) ? cnt[b * n + i] : 0;
  buf[t] = v;
  __syncthreads();
  for (int d = 1; d < 256; d <<= 1) {
    int add = (t >= d) ? buf[t - d] : 0;
    __syncthreads();
    buf[t] += add;
    __syncthreads();
  }
  if (i < n) incl[b * n + i] = buf[t];
  if (t == 255) bsum[b * 256 + blockIdx.x] = buf[255];
}

__global__ void scan2_kernel(int* __restrict__ bsum, int nb) {
  __shared__ int buf[256];
  int b = blockIdx.x;
  int t = threadIdx.x;
  int v = (t < nb) ? bsum[b * 256 + t] : 0;
  buf[t] = v;
  __syncthreads();
  for (int d = 1; d < 256; d <<= 1) {
    int add = (t >= d) ? buf[t - d] : 0;
    __syncthreads();
    buf[t] += add;
    __syncthreads();
  }
  if (t < nb) bsum[b * 256 + t] = buf[t] - v;
}

__global__ void scan3_kernel(const int* __restrict__ cnt, const int* __restrict__ incl,
                             const int* __restrict__ bsum, int* __restrict__ offs,
                             int* __restrict__ cursor, int n) {
  int b = blockIdx.y;
  int i = blockIdx.x * 256 + threadIdx.x;
  if (i < n) {
    int e = incl[b * n + i] - cnt[b * n + i] + bsum[b * 256 + blockIdx.x];
    offs[b * (n + 1) + i] = e;
    cursor[b * n + i] = e;
    if (i == n - 1) offs[b * (n + 1) + n] = incl[b * n + i] + bsum[b * 256 + blockIdx.x];
  }
}

__global__ void fill_kernel(const int* __restrict__ dA, const int* __restrict__ dB,
                            int* __restrict__ cursor, int* __restrict__ perm, int E, int N) {
  int b = blockIdx.y;
  const int* dst = b ? dB : dA;
  int e = blockIdx.x * 256 + threadIdx.x;
  if (e < E) {
    int p = atomicAdd(&cursor[b * N + dst[e]], 1);
    perm[(size_t)b * E + p] = e;
  }
}

// ------- sort each node's segment by edge id (LDS scratch), both branches -------------
__global__ __launch_bounds__(64) void sortseg_kernel(const int* __restrict__ off,
                                                     int* __restrict__ perm, int N, int E) {
  __shared__ int loc[64 * 64];
  int b = blockIdx.y;
  const int* offb = off + b * (N + 1);
  int* permb = perm + (size_t)b * E;
  int t = threadIdx.x;
  int n = blockIdx.x * 64 + t;
  if (n >= N) return;
  int e0 = offb[n], e1 = offb[n + 1];
  int d = e1 - e0;
  if (d <= 1) return;
  if (d <= 64) {
    for (int i = 0; i < d; i++) loc[i * 64 + t] = permb[e0 + i];
    for (int i = 1; i < d; i++) {
      int v = loc[i * 64 + t];
      int j = i - 1;
      while (j >= 0 && loc[j * 64 + t] > v) { loc[(j + 1) * 64 + t] = loc[j * 64 + t]; j--; }
      loc[(j + 1) * 64 + t] = v;
    }
    for (int i = 0; i < d; i++) permb[e0 + i] = loc[i * 64 + t];
  } else {
    for (int i = 0; i < d - 1; i++) {
      int mi = i;
      for (int j = i + 1; j < d; j++)
        if (permb[e0 + j] < permb[e0 + mi]) mi = j;
      int tmp = permb[e0 + i];
      permb[e0 + i] = permb[e0 + mi];
      permb[e0 + mi] = tmp;
    }
  }
}

// -------- src_csr[i] = src[perm[i]]; ipos[perm[i]] = i (both branches) ----------------
__global__ void srccsr_kernel(const int* __restrict__ sA, const int* __restrict__ sB,
                              const int* __restrict__ perm, int* __restrict__ src_csr,
                              int* __restrict__ ipos, int E) {
  int b = blockIdx.y;
  const int* src = b ? sB : sA;
  int i = blockIdx.x * 256 + threadIdx.x;
  if (i < E) {
    int e = perm[(size_t)b * E + i];
    src_csr[(size_t)b * E + i] = src[e];
    ipos[(size_t)b * E + e] = i;
  }
}

// ------- EdgeGraphConv: wave-per-node; hn uint loads 2 edges/step, he_csr sequential ---
__global__ __launch_bounds__(256) void edgeconv_kernel(const int* __restrict__ off,
                                                       const int* __restrict__ src_csr,
                                                       const __half* __restrict__ hn,
                                                       const __half* __restrict__ he_csr,
                                                       __half* __restrict__ xsum, int N, int E) {
  int b = blockIdx.y;
  const int* offb = off + b * (N + 1);
  const int* scb = src_csr + (size_t)b * E;
  const unsigned* hnu = (const unsigned*)(hn + (size_t)b * N * 64);
  const __half* heb = he_csr + (size_t)b * E * 16;
  int wave = threadIdx.x >> 6, lane = threadIdx.x & 63;
  int n = blockIdx.x * 4 + wave;
  if (n >= N) return;
  int e0 = offb[n], e1 = offb[n + 1];
  int hl = lane & 31, pr = lane >> 5;  // half-lane (feature pair), parity (edge)
  float ax = 0.f, ay = 0.f;
  int eg = e0;
  for (; eg + 8 <= e1; eg += 8) {
    int ea = eg + pr;
    int s0 = scb[ea], s1 = scb[ea + 2], s2 = scb[ea + 4], s3 = scb[ea + 6];
    unsigned w0 = hnu[(size_t)s0 * 32 + hl];
    unsigned w1 = hnu[(size_t)s1 * 32 + hl];
    unsigned w2 = hnu[(size_t)s2 * 32 + hl];
    unsigned w3 = hnu[(size_t)s3 * 32 + hl];
    float2 f0 = __half22float2(*(__half2*)&w0);
    float2 f1 = __half22float2(*(__half2*)&w1);
    float2 f2 = __half22float2(*(__half2*)&w2);
    float2 f3 = __half22float2(*(__half2*)&w3);
    ax += f0.x; ay += f0.y;
    ax += f1.x; ay += f1.y;
    ax += f2.x; ay += f2.y;
    ax += f3.x; ay += f3.y;
  }
  for (; eg + 2 <= e1; eg += 2) {
    int s0 = scb[eg + pr];
    unsigned w0 = hnu[(size_t)s0 * 32 + hl];
    float2 f0 = __half22float2(*(__half2*)&w0);
    ax += f0.x; ay += f0.y;
  }
  if (eg < e1 && pr == 0) {
    int s0 = scb[eg];
    unsigned w0 = hnu[(size_t)s0 * 32 + hl];
    float2 f0 = __half22float2(*(__half2*)&w0);
    ax += f0.x; ay += f0.y;
  }
  ax += __shfl_xor(ax, 32);
  ay += __shfl_xor(ay, 32);
  int grp = lane >> 4, f = lane & 15;
  float hacc = 0.f;
  for (int e = e0 + grp; e < e1; e += 4) hacc += __half2float(heb[(size_t)e * 16 + f]);
  hacc += __shfl_xor(hacc, 16);
  hacc += __shfl_xor(hacc, 32);
  __half* xr = xsum + (size_t)b * N * 80 + (size_t)n * 80;
  if (lane < 32) {
    __half2 h2;
    h2.x = __float2half(ax);
    h2.y = __float2half(ay);
    *(__half2*)&xr[hl * 2] = h2;
  }
  if (lane < 16) xr[64 + lane] = __float2half(hacc);
}

// ---------------- attention el/er (both branches) ----------------
__global__ __launch_bounds__(256) void attn_lr_kernel(const __half* __restrict__ z,
                                                      const void* __restrict__ al,
                                                      const void* __restrict__ ar, size_t astr,
                                                      const int* __restrict__ pflag,
                                                      float* __restrict__ el,
                                                      float* __restrict__ er, int N) {
  const bool pb = (*pflag != 0);
  const int b = blockIdx.y;
  const size_t off = (size_t)b * astr;
  const __half* zb = z + (size_t)b * N * 512;
  int n = (blockIdx.x * blockDim.x + threadIdx.x) >> 6;
  int lane = threadIdx.x & 63;
  if (n >= N) return;
  union { uint4 q; __half s[8]; } u;
  u.q = *(const uint4*)(zb + (size_t)n * 512 + lane * 8);
  float sl = 0.f, sr = 0.f;
#pragma unroll
  for (int q = 0; q < 8; q++) {
    int idx = lane * 8 + q;
    float zv = __half2float(u.s[q]);
    sl += zv * ldf(al, off + idx, pb);
    sr += zv * ldf(ar, off + idx, pb);
  }
#pragma unroll
  for (int o = 1; o < 16; o <<= 1) {
    sl += __shfl_xor(sl, o);
    sr += __shfl_xor(sr, o);
  }
  if ((lane & 15) == 0) {
    int h = lane >> 4;
    el[(size_t)b * N * 4 + n * 4 + h] = sl;
    er[(size_t)b * N * 4 + n * 4 + h] = sr;
  }
}

// ------- per-node attn exp in CSR order + denominator (both branches) -----------------
__global__ void attn_sden_kernel(const int* __restrict__ off, const int* __restrict__ src_csr,
                                 const float* __restrict__ el, const float* __restrict__ er,
                                 float* __restrict__ ecsr, float* __restrict__ sden, int N, int E) {
  int b = blockIdx.y;
  const int* offb = off + b * (N + 1);
  const int* scb = src_csr + (size_t)b * E;
  const float* elb = el + (size_t)b * N * 4;
  float* ecb = ecsr + (size_t)b * E * 4;
  int idx = blockIdx.x * 256 + threadIdx.x;
  int n = idx >> 2, h = idx & 3;
  if (n >= N) return;
  int e0 = offb[n], e1 = offb[n + 1];
  float ern = er[(size_t)b * N * 4 + n * 4 + h];
  float s = 0.f;
  for (int eg = e0; eg < e1; eg++) {
    float v = elb[scb[eg] * 4 + h] + ern;
    v = v > 0.f ? v : 0.2f * v;
    v = fminf(v, 60.f);
    float ev = expf(v);
    ecb[eg * 4 + h] = ev;
    s += ev;
  }
  sden[(size_t)b * N * 4 + n * 4 + h] = s;
}

// ---------------- lean GAT gather (both branches), 4-way ILP, fp16 out ----------------
__global__ __launch_bounds__(256) void gat_gather_kernel(const int* __restrict__ off,
                                                         const int* __restrict__ src_csr,
                                                         const __half* __restrict__ z,
                                                         const float* __restrict__ ecsr,
                                                         const float* __restrict__ sden,
                                                         const void* __restrict__ gb, size_t gstr,
                                                         const int* __restrict__ pflag,
                                                         __half* __restrict__ out, int N, int E) {
  const bool pb = (*pflag != 0);
  int b = blockIdx.y;
  const int* offb = off + b * (N + 1);
  const int* scb = src_csr + (size_t)b * E;
  const __half* zb = z + (size_t)b * N * 512;
  const float* ecb = ecsr + (size_t)b * E * 4;
  const size_t goff = (size_t)b * gstr;
  int n = (blockIdx.x * blockDim.x + threadIdx.x) >> 6;
  int lane = threadIdx.x & 63;
  if (n >= N) return;
  int h = lane >> 4;
  float sd = sden[(size_t)b * N * 4 + n * 4 + h];
  float sinv = sd > 0.f ? 1.f / sd : 0.f;
  float acc[8] = {0.f, 0.f, 0.f, 0.f, 0.f, 0.f, 0.f, 0.f};
  int e0 = offb[n], e1 = offb[n + 1];
  int eg = e0;
  for (; eg + 4 <= e1; eg += 4) {
    int s0 = scb[eg], s1 = scb[eg + 1], s2 = scb[eg + 2], s3 = scb[eg + 3];
    float a0 = ecb[(eg) * 4 + h] * sinv;
    float a1 = ecb[(eg + 1) * 4 + h] * sinv;
    float a2 = ecb[(eg + 2) * 4 + h] * sinv;
    float a3 = ecb[(eg + 3) * 4 + h] * sinv;
    union { uint4 q; __half s[8]; } u0, u1, u2, u3;
    u0.q = *(const uint4*)(zb + (size_t)s0 * 512 + lane * 8);
    u1.q = *(const uint4*)(zb + (size_t)s1 * 512 + lane * 8);
    u2.q = *(const uint4*)(zb + (size_t)s2 * 512 + lane * 8);
    u3.q = *(const uint4*)(zb + (size_t)s3 * 512 + lane * 8);
#pragma unroll
    for (int q = 0; q < 8; q++) acc[q] += a0 * __half2float(u0.s[q]);
#pragma unroll
    for (int q = 0; q < 8; q++) acc[q] += a1 * __half2float(u1.s[q]);
#pragma unroll
    for (int q = 0; q < 8; q++) acc[q] += a2 * __half2float(u2.s[q]);
#pragma unroll
    for (int q = 0; q < 8; q++) acc[q] += a3 * __half2float(u3.s[q]);
  }
  for (; eg < e1; eg++) {
    int s0 = scb[eg];
    float a0 = ecb[eg * 4 + h] * sinv;
    union { uint4 q; __half s[8]; } u0;
    u0.q = *(const uint4*)(zb + (size_t)s0 * 512 + lane * 8);
#pragma unroll
    for (int q = 0; q < 8; q++) acc[q] += a0 * __half2float(u0.s[q]);
  }
  union { uint4 q; __half s[8]; } w;
#pragma unroll
  for (int q = 0; q < 8; q++) {
    float v = acc[q] + ldf(gb, goff + lane * 8 + q, pb);
    w.s[q] = __float2half(v > 0.f ? v : 0.01f * v);
  }
  *(uint4*)(out + (size_t)b * N * 512 + (size_t)n * 512 + lane * 8) = w.q;
}

// ---------------- node weight (both branches) ----------------
__global__ __launch_bounds__(256) void wnode_kernel(const float* __restrict__ x,
                                                    const void* __restrict__ wsw,
                                                    const void* __restrict__ wsb,
                                                    const int* __restrict__ pflag,
                                                    float* __restrict__ w, int N) {
  const bool pb = (*pflag != 0);
  int b = blockIdx.y;
  const float* xb = x + (size_t)b * N * 128;
  size_t woff = (size_t)b * 128, boff = (size_t)b;
  int n = (blockIdx.x * blockDim.x + threadIdx.x) >> 6;
  int lane = threadIdx.x & 63;
  if (n >= N) return;
  float s = xb[(size_t)n * 128 + lane] * ldf(wsw, woff + lane, pb) +
            xb[(size_t)n * 128 + 64 + lane] * ldf(wsw, woff + 64 + lane, pb);
#pragma unroll
  for (int o = 1; o < 64; o <<= 1) s += __shfl_xor(s, o);
  if (lane == 0) {
    float t = s + ldf(wsb, boff, pb);
    t = fmaxf(fminf(t, 60.f), -60.f);
    w[(size_t)b * N + n] = 1.f / (1.f + expf(-t));
  }
}

__device__ __forceinline__ int lower_bound_dev(const int* a, int n, int v) {
  int lo = 0, hi = n;
  while (lo < hi) {
    int mid = (lo + hi) >> 1;
    if (a[mid] < v) lo = mid + 1; else hi = mid;
  }
  return lo;
}

// ---------------- readout phase 1 (both branches) ----------------
__global__ __launch_bounds__(128) void readout_p1_kernel(const float* __restrict__ x,
                                                         const float* __restrict__ w,
                                                         const int* __restrict__ gidA,
                                                         const int* __restrict__ gidB, int N,
                                                         double* __restrict__ psum,
                                                         float* __restrict__ pmax) {
  int b = blockIdx.y;
  const int* gid = b ? gidB : gidA;
  const float* xb = x + (size_t)b * N * 128;
  const float* wb = w + (size_t)b * N;
  int g = blockIdx.x >> 4;
  int c = blockIdx.x & 15;
  int d = threadIdx.x;
  __shared__ int ss, se;
  if (d == 0) {
    ss = lower_bound_dev(gid, N, g);
    se = lower_bound_dev(gid, N, g + 1);
  }
  __syncthreads();
  int len = se - ss;
  int a = ss + (int)(((long)len * c) >> 4);
  int bb = ss + (int)(((long)len * (c + 1)) >> 4);
  double s = 0.0;
  float m = -1e30f;
  for (int n = a; n < bb; n++) {
    float v = xb[(size_t)n * 128 + d];
    s += (double)v * (double)wb[n];
    m = fmaxf(m, v);
  }
  psum[((size_t)b * Bg * 16 + blockIdx.x) * 128 + d] = s;
  pmax[((size_t)b * Bg * 16 + blockIdx.x) * 128 + d] = m;
}

// ---------------- readout phase 2 (both branches) ----------------
__global__ __launch_bounds__(128) void readout_p2_kernel(const double* __restrict__ psum,
                                                         const float* __restrict__ pmax,
                                                         float* __restrict__ hs,
                                                         float* __restrict__ hm) {
  int b = blockIdx.y;
  int g = blockIdx.x, d = threadIdx.x;
  double s = 0.0;
  float m = -1e30f;
#pragma unroll
  for (int c = 0; c < 16; c++) {
    s += psum[((size_t)b * Bg * 16 + g * 16 + c) * 128 + d];
    m = fmaxf(m, pmax[((size_t)b * Bg * 16 + g * 16 + c) * 128 + d]);
  }
  hs[(size_t)b * Bg * 128 + g * 128 + d] = (float)s;
  hm[(size_t)b * Bg * 128 + g * 128 + d] = m;
}

// ---------------- pool linear (both branches) ----------------
__global__ __launch_bounds__(128) void pool_kernel(const float* __restrict__ hs,
                                                   const float* __restrict__ hm,
                                                   const void* __restrict__ Wp,
                                                   const void* __restrict__ bp,
                                                   const int* __restrict__ pflag,
                                                   float* __restrict__ bout) {
  const bool pb = (*pflag != 0);
  int b = blockIdx.y;
  size_t woff = (size_t)b * 256 * 128, boff = (size_t)b * 128;
  int g = blockIdx.x, j = threadIdx.x;
  __shared__ float hg[256];
  hg[j] = hs[(size_t)b * Bg * 128 + g * 128 + j];
  hg[128 + j] = hm[(size_t)b * Bg * 128 + g * 128 + j];
  __syncthreads();
  double acc = (double)ldf(bp, boff + j, pb);
  for (int k = 0; k < 256; k++) acc += (double)hg[k] * (double)ldf(Wp, woff + (size_t)k * 128 + j, pb);
  bout[(size_t)b * Bg * 128 + g * 128 + j] = (float)acc;
}

// ---------------- final head ----------------
__global__ __launch_bounds__(128) void head_kernel(const float* __restrict__ bA,
                                                   const float* __restrict__ bB,
                                                   const void* __restrict__ Wo1,
                                                   const void* __restrict__ bo1,
                                                   const void* __restrict__ Wo2,
                                                   const void* __restrict__ bo2,
                                                   const int* __restrict__ pflag,
                                                   const int* __restrict__ oflag,
                                                   void* __restrict__ out) {
  const bool pb = (*pflag != 0);
  int g = blockIdx.x, j = threadIdx.x;
  __shared__ float zr[256];
  __shared__ double t[128];
  zr[j] = bA[g * 128 + j];
  zr[128 + j] = bB[g * 128 + j];
  __syncthreads();
  double acc = (double)ldf(bo1, j, pb);
  for (int k = 0; k < 256; k++) acc += (double)zr[k] * (double)ldf(Wo1, (size_t)k * 128 + j, pb);
  if (acc < 0.0) acc *= 0.01;
  t[j] = acc * (double)ldf(Wo2, j, pb);
  __syncthreads();
  for (int sdt = 64; sdt > 0; sdt >>= 1) {
    if (j < sdt) t[j] += t[j + sdt];
    __syncthreads();
  }
  if (j == 0) {
    float v = (float)(t[0] + (double)ldf(bo2, 0, pb));
    if (*oflag) ((bf16*)out)[g] = __float2bfloat16(v);
    else ((float*)out)[g] = v;
  }
}

extern "C" void kernel_launch(void* const* d_in, const int* in_sizes, int n_in,
                              void* d_out, int out_size, void* d_ws, size_t ws_size,
                              hipStream_t stream) {
  const int* srcA = (const int*)d_in[0];
  const int* dstA = (const int*)d_in[1];
  const int* gidA = (const int*)d_in[2];
  const void* nfA = d_in[3];
  const void* efA = d_in[4];
  const int* srcB = (const int*)d_in[5];
  const int* dstB = (const int*)d_in[6];
  const int* gidB = (const int*)d_in[7];
  const void* nfB = d_in[8];
  const void* efB = d_in[9];
  const void* p_Wn = d_in[10];
  const void* p_bn = d_in[11];
  const void* p_We = d_in[12];
  const void* p_be = d_in[13];
  const void* p_Wc = d_in[14];
  const void* p_bc = d_in[15];
  const void* p_fc1 = d_in[16];
  const void* p_al1 = d_in[17];
  const void* p_ar1 = d_in[18];
  const void* p_gb1 = d_in[19];
  const void* p_Wl1 = d_in[20];
  const void* p_bl1 = d_in[21];
  const void* p_fc2 = d_in[22];
  const void* p_al2 = d_in[23];
  const void* p_ar2 = d_in[24];
  const void* p_gb2 = d_in[25];
  const void* p_Wl2 = d_in[26];
  const void* p_bl2 = d_in[27];
  const void* p_ws_w = d_in[28];
  const void* p_ws_b = d_in[29];
  const void* p_Wp = d_in[30];
  const void* p_bp = d_in[31];
  const void* Wo1 = d_in[32];
  const void* bo1 = d_in[33];
  const void* Wo2 = d_in[34];
  const void* bo2 = d_in[35];

  // workspace carve-up (~146 MB)
  char* wp = (char*)d_ws;
  auto alloc = [&](size_t bytes) -> char* {
    char* p = wp;
    wp += (bytes + 255) & ~(size_t)255;
    return p;
  };
  int* flags = (int*)alloc(2 * 4);
  int* cnt = (int*)alloc((size_t)2 * Nn * 4);
  int* incl = (int*)alloc((size_t)2 * Nn * 4);
  int* bsum = (int*)alloc(2 * 256 * 4);
  int* offs = (int*)alloc((size_t)2 * (Nn + 1) * 4);
  int* cursor = (int*)alloc((size_t)2 * Nn * 4);
  int* perm = (int*)alloc((size_t)2 * Ne * 4);
  int* src_csr = (int*)alloc((size_t)2 * Ne * 4);
  int* ipos = (int*)alloc((size_t)2 * Ne * 4);
  float* ecsr = (float*)alloc((size_t)2 * Ne * 4 * 4);
  float* sden = (float*)alloc((size_t)2 * Nn * 4 * 4);
  float* el = (float*)alloc((size_t)2 * Nn * 4 * 4);
  float* er = (float*)alloc((size_t)2 * Nn * 4 * 4);
  float* wn = (float*)alloc((size_t)2 * Nn * 4);
  double* psum = (double*)alloc((size_t)2 * Bg * 16 * 128 * 8);
  float* pmax = (float*)alloc((size_t)2 * Bg * 16 * 128 * 4);
  float* hsb = (float*)alloc((size_t)2 * Bg * 128 * 4);
  float* hmb = (float*)alloc((size_t)2 * Bg * 128 * 4);
  float* bout = (float*)alloc((size_t)2 * Bg * 128 * 4);
  // transposed fp16 weight planes
  __half* Wct = (__half*)alloc((size_t)2 * 80 * 80 * 2);
  __half* fc1t = (__half*)alloc((size_t)2 * 512 * 80 * 2);
  __half* Wl1t = (__half*)alloc((size_t)2 * 128 * 512 * 2);
  __half* fc2t = (__half*)alloc((size_t)2 * 512 * 128 * 2);
  __half* Wl2t = (__half*)alloc((size_t)2 * 128 * 512 * 2);
  // big overlaid regions
  char* R = alloc((size_t)2 * Nn * 512 * 2);   // he_csr+hn early -> z -> x2
  char* H = alloc((size_t)2 * Nn * 512 * 2);   // xsum early -> hb
  __half* xcx1 = (__half*)alloc((size_t)2 * Nn * 128 * 2);
  // overlays
  __half* he_csr = (__half*)R;
  __half* hn = (__half*)(R + (size_t)2 * Ne * 16 * 2);
  __half* z = (__half*)R;
  float* x2 = (float*)R;
  __half* xsum = (__half*)H;
  __half* hb = (__half*)H;
  __half* xc = xcx1;
  __half* x1 = xcx1;

  auto cdiv = [](int a, int b) { return (a + b - 1) / b; };

  detect_kernel<<<1, 256, 0, stream>>>((const u16*)nfA, 8192, (const u16*)p_fc1, 8192, flags);
  int* fflag = &flags[0];
  int* pflag = &flags[1];

  // prep: fused transpose+convert of all fp16 weight planes (both branches)
  {
    TCAll tc;
    int segK[5] = {80, 80, 512, 128, 512};
    int segN[5] = {80, 512, 128, 512, 128};
    const void* segW[5] = {p_Wc, p_fc1, p_Wl1, p_fc2, p_Wl2};
    __half* segH[5] = {Wct, fc1t, Wl1t, fc2t, Wl2t};
    int start = 0, s = 0;
    for (int i = 0; i < 2; i++)
      for (int m = 0; m < 5; m++) {
        int sz = segK[m] * segN[m];
        tc.t[s].W = segW[m];
        tc.t[s].off = (size_t)i * sz;
        tc.t[s].H = segH[m] + (size_t)i * sz;
        tc.t[s].K = segK[m];
        tc.t[s].N = segN[m];
        tc.t[s].start = start;
        start += sz;
        s++;
      }
    tc.total = start;
    transconv_all_kernel<<<cdiv(start, 256), 256, 0, stream>>>(tc, pflag);
  }

  const int nb = cdiv(Nn, 256);

  // ---- merged front-end (both branches in every dispatch) ----
  hipMemsetAsync(cnt, 0, (size_t)2 * Nn * 4, stream);
  count_kernel<<<dim3(cdiv(Ne, 256), 2), 256, 0, stream>>>(dstA, dstB, cnt, Ne, Nn);
  scan1_kernel<<<dim3(nb, 2), 256, 0, stream>>>(cnt, incl, bsum, Nn);
  scan2_kernel<<<2, 256, 0, stream>>>(bsum, nb);
  scan3_kernel<<<dim3(nb, 2), 256, 0, stream>>>(cnt, incl, bsum, offs, cursor, Nn);
  fill_kernel<<<dim3(cdiv(Ne, 256), 2), 256, 0, stream>>>(dstA, dstB, cursor, perm, Ne, Nn);
  sortseg_kernel<<<dim3(cdiv(Nn, 64), 2), 64, 0, stream>>>(offs, perm, Nn, Ne);
  srccsr_kernel<<<dim3(cdiv(Ne, 256), 2), 256, 0, stream>>>(srcA, srcB, perm, src_csr, ipos, Ne);
  proj_nf_kernel<<<dim3(cdiv(Nn, 4), 2), 256, 0, stream>>>(
      nfA, nfB, fflag, p_Wn, p_bn, pflag, hn, Nn);
  proj_ef_kernel<<<dim3(cdiv(Ne, 16), 2), 256, 0, stream>>>(
      efA, efB, fflag, p_We, p_be, pflag, ipos, he_csr, Ne);
  edgeconv_kernel<<<dim3(cdiv(Nn, 4), 2), 256, 0, stream>>>(
      offs, src_csr, hn, he_csr, xsum, Nn, Ne);

  const int gm = cdiv(Nn, 128);

  // ---- main pipeline, both branches per dispatch ----
  mfma_f16_gemm<1, 2><<<dim3(gm, 1, 2), 256, 0, stream>>>(
      xsum, (size_t)Nn * 80, Wct, 6400, p_bc, 80, pflag, xc, (size_t)Nn * 80, Nn, 80, 80);
  // GAT 1
  mfma_f16_gemm<0, 2><<<dim3(gm, 4, 2), 256, 0, stream>>>(
      xc, (size_t)Nn * 80, fc1t, (size_t)512 * 80, nullptr, 0, pflag, z, (size_t)Nn * 512,
      Nn, 80, 512);
  attn_lr_kernel<<<dim3(cdiv(Nn * 64, 256), 2), 256, 0, stream>>>(
      z, p_al1, p_ar1, 512, pflag, el, er, Nn);
  attn_sden_kernel<<<dim3(cdiv(Nn * 4, 256), 2), 256, 0, stream>>>(
      offs, src_csr, el, er, ecsr, sden, Nn, Ne);
  gat_gather_kernel<<<dim3(cdiv(Nn * 64, 256), 2), 256, 0, stream>>>(
      offs, src_csr, z, ecsr, sden, p_gb1, 512, pflag, hb, Nn, Ne);
  mfma_f16_gemm<0, 2><<<dim3(gm, 1, 2), 256, 0, stream>>>(
      hb, (size_t)Nn * 512, Wl1t, (size_t)128 * 512, p_bl1, 128, pflag, x1, (size_t)Nn * 128,
      Nn, 512, 128);
  // GAT 2
  mfma_f16_gemm<0, 2><<<dim3(gm, 4, 2), 256, 0, stream>>>(
      x1, (size_t)Nn * 128, fc2t, (size_t)512 * 128, nullptr, 0, pflag, z, (size_t)Nn * 512,
      Nn, 128, 512);
  attn_lr_kernel<<<dim3(cdiv(Nn * 64, 256), 2), 256, 0, stream>>>(
      z, p_al2, p_ar2, 512, pflag, el, er, Nn);
  attn_sden_kernel<<<dim3(cdiv(Nn * 4, 256), 2), 256, 0, stream>>>(
      offs, src_csr, el, er, ecsr, sden, Nn, Ne);
  gat_gather_kernel<<<dim3(cdiv(Nn * 64, 256), 2), 256, 0, stream>>>(
      offs, src_csr, z, ecsr, sden, p_gb2, 512, pflag, hb, Nn, Ne);
  mfma_f16_gemm<0, 0><<<dim3(gm, 1, 2), 256, 0, stream>>>(
      hb, (size_t)Nn * 512, Wl2t, (size_t)128 * 512, p_bl2, 128, pflag, x2, (size_t)Nn * 128,
      Nn, 512, 128);
  // readout
  wnode_kernel<<<dim3(cdiv(Nn * 64, 256), 2), 256, 0, stream>>>(
      x2, p_ws_w, p_ws_b, pflag, wn, Nn);
  readout_p1_kernel<<<dim3(Bg * 16, 2), 128, 0, stream>>>(x2, wn, gidA, gidB, Nn, psum, pmax);
  readout_p2_kernel<<<dim3(Bg, 2), 128, 0, stream>>>(psum, pmax, hsb, hmb);
  pool_kernel<<<dim3(Bg, 2), 128, 0, stream>>>(hsb, hmb, p_Wp, p_bp, pflag, bout);

  head_kernel<<<Bg, 128, 0, stream>>>(bout, bout + (size_t)Bg * 128, Wo1, bo1, Wo2, bo2,
                                      pflag, fflag, d_out);
}